// Round 1
// baseline (318.309 us; speedup 1.0000x reference)
//
#include <hip/hip_runtime.h>
#include <hip/hip_cooperative_groups.h>
#include <hip/hip_bf16.h>
#include <math.h>

namespace cg = cooperative_groups;

#define BATCH   8192
#define NFIELD  24
#define FAC     16
#define PAIRS   276
#define NSETS   24             // 23 real 12-pair sets + 1 idle set
#define SETLEN  12
#define NBB     (BATCH / 64)   // 128 batch blocks of 64 rows

typedef __attribute__((ext_vector_type(8))) __bf16 bf16x8;
typedef __attribute__((ext_vector_type(4))) float f32x4;

// ---- workspace layout (bytes) ----
#define XVT_OFF   0
#define COMBO_OFF 6291456
#define PART_OFF  (COMBO_OFF + 1285632)
#define WVAL_OFF  (PART_OFF + 786432)
#define CONST_OFF (WVAL_OFF + 786432)

// ---------------- shared phase bodies (single-sourced for fused + split) ----

// One (field,b) gather unit: v-row -> bf16 xvT slab + linear term.
__device__ __forceinline__ void do_gather(int blk, int tid,
        const int* __restrict__ inputs, const float* __restrict__ v,
        const float* __restrict__ w,
        __hip_bfloat16* __restrict__ xvT, float* __restrict__ wval) {
    int t = blk * 256 + tid;                  // < 196608
    int field = t >> 13;
    int b = t & 8191;
    int idx = inputs[b * NFIELD + field];
    const float4* src = (const float4*)(v + (long)idx * FAC);
    union { __hip_bfloat16 h[16]; uint4 u[2]; } tmp;
    float4 a0 = src[0], a1 = src[1], a2 = src[2], a3 = src[3];
    tmp.h[0]  = __float2bfloat16(a0.x); tmp.h[1]  = __float2bfloat16(a0.y);
    tmp.h[2]  = __float2bfloat16(a0.z); tmp.h[3]  = __float2bfloat16(a0.w);
    tmp.h[4]  = __float2bfloat16(a1.x); tmp.h[5]  = __float2bfloat16(a1.y);
    tmp.h[6]  = __float2bfloat16(a1.z); tmp.h[7]  = __float2bfloat16(a1.w);
    tmp.h[8]  = __float2bfloat16(a2.x); tmp.h[9]  = __float2bfloat16(a2.y);
    tmp.h[10] = __float2bfloat16(a2.z); tmp.h[11] = __float2bfloat16(a2.w);
    tmp.h[12] = __float2bfloat16(a3.x); tmp.h[13] = __float2bfloat16(a3.y);
    tmp.h[14] = __float2bfloat16(a3.z); tmp.h[15] = __float2bfloat16(a3.w);
    int bb = b >> 6, row = b & 63;
    __hip_bfloat16* base = xvT + (long)bb * 24576 + field * 1024 + row * 8;
    *(uint4*)base         = tmp.u[0];
    *(uint4*)(base + 512) = tmp.u[1];
    wval[field * BATCH + b] = w[idx];
}

// One (pair p, lane-unit L in [0,64)) weight-repack unit.
__device__ __forceinline__ void do_repack(int p, int L,
        const float* __restrict__ W1, const float* __restrict__ W2,
        const float* __restrict__ b1, char* __restrict__ combo) {
    int q = L >> 4, c = L & 15;
    char* base = combo + (long)p * 4608;
    union { __hip_bfloat16 h[8]; uint4 u; } buf;
#pragma unroll
    for (int tt = 0; tt < 4; ++tt) {
#pragma unroll
        for (int jj = 0; jj < 8; ++jj)
            buf.h[jj] = __float2bfloat16(W1[p * 2048 + (q * 8 + jj) * 64 + tt * 16 + c]);
        *(uint4*)(base + 512 + tt * 1024 + L * 16) = buf.u;
    }
    if (L < 16) {
        float4 bv = {b1[p * 64 + L], b1[p * 64 + 16 + L], b1[p * 64 + 32 + L], b1[p * 64 + 48 + L]};
        *(float4*)(base + L * 16) = bv;
        float4 wv = {W2[p * 64 + L], W2[p * 64 + 16 + L], W2[p * 64 + 32 + L], W2[p * 64 + 48 + L]};
        *(float4*)(base + 256 + L * 16) = wv;
    }
}

__device__ __forceinline__ void do_padzero(int tid, char* __restrict__ combo) {
    uint4 z = {0, 0, 0, 0};
    for (int k = tid; k < 576; k += 256)
        *(uint4*)(combo + (long)PAIRS * 4608 + k * 16) = z;
}

// b2 sum + global bias -> consts[0]. red must be >= 256 floats of LDS.
__device__ __forceinline__ void do_b2sum(int tid, float* red,
        const float* __restrict__ b2, const float* __restrict__ bsc,
        float* __restrict__ consts) {
    float s = 0.f;
    for (int k = tid; k < PAIRS; k += 256) s += b2[k];
    red[tid] = s;
    __syncthreads();
    for (int off = 128; off > 0; off >>= 1) {
        if (tid < off) red[tid] += red[tid + off];
        __syncthreads();
    }
    if (tid == 0) consts[0] = red[0] + bsc[0];
}

// One pair's weight package in registers. Bias pre-broadcast into persistent
// MFMA C-operands (D!=C, so cb survives and is reused across all 4 row-tiles).
struct Pkg {
    f32x4 cb0, cb1, cb2, cb3;
    float4 mw;
    bf16x8 f0, f1, f2, f3;
};

__device__ __forceinline__ Pkg load_pkg(const char* p, int mcol, int l16) {
    Pkg k;
    float4 tb = *(const float4*)(p + mcol);
    k.cb0 = (f32x4){tb.x, tb.x, tb.x, tb.x};
    k.cb1 = (f32x4){tb.y, tb.y, tb.y, tb.y};
    k.cb2 = (f32x4){tb.z, tb.z, tb.z, tb.z};
    k.cb3 = (f32x4){tb.w, tb.w, tb.w, tb.w};
    k.mw = *(const float4*)(p + 256 + mcol);
    k.f0 = *(const bf16x8*)(p + 512  + l16);
    k.f1 = *(const bf16x8*)(p + 1536 + l16);
    k.f2 = *(const bf16x8*)(p + 2560 + l16);
    k.f3 = *(const bf16x8*)(p + 3584 + l16);
    return k;
}

// Apply one package to all 4 row-tiles. Packed-f32 epilogue (v_max/v_pk_fma).
#define PKGCOMP(P)                                                            \
    {                                                                         \
        int fso = ((quad < 2) ? i : j) * 1088;                                \
        const f32x4 z4 = {0.f, 0.f, 0.f, 0.f};                                \
        _Pragma("unroll")                                                     \
        for (int t = 0; t < 4; ++t) {                                         \
            bf16x8 af = *(const bf16x8*)(xv_s + fso + abase + t * 128);       \
            f32x4 c0 = __builtin_amdgcn_mfma_f32_16x16x32_bf16(af, P.f0, P.cb0, 0, 0, 0); \
            f32x4 c1 = __builtin_amdgcn_mfma_f32_16x16x32_bf16(af, P.f1, P.cb1, 0, 0, 0); \
            f32x4 c2 = __builtin_amdgcn_mfma_f32_16x16x32_bf16(af, P.f2, P.cb2, 0, 0, 0); \
            f32x4 c3 = __builtin_amdgcn_mfma_f32_16x16x32_bf16(af, P.f3, P.cb3, 0, 0, 0); \
            acc[t] = acc[t] + __builtin_elementwise_max(c0, z4) * P.mw.x;     \
            acc[t] = acc[t] + __builtin_elementwise_max(c1, z4) * P.mw.y;     \
            acc[t] = acc[t] + __builtin_elementwise_max(c2, z4) * P.mw.z;     \
            acc[t] = acc[t] + __builtin_elementwise_max(c3, z4) * P.mw.w;     \
        }                                                                     \
        ++j;                                                                  \
        if (j == NFIELD) { ++i; j = i + 1; }                                  \
    }

// MFMA main phase: one 64-row slab in LDS shared by 4 waves; each wave owns a
// distinct 12-pair set, barrier-free K-loop, depth-2 two-set register prefetch.
__device__ __forceinline__ void do_main(int blk, int tid,
        __hip_bfloat16* xv_s,
        const __hip_bfloat16* __restrict__ xvT,
        const char* __restrict__ combo,
        float* __restrict__ partial) {
    int bb   = blk & (NBB - 1);
    int pg   = blk >> 7;                 // 0..5
    int lane = tid & 63;
    int wave = tid >> 6;
    int col  = lane & 15;
    int quad = lane >> 4;

    // stage 48KB slab: 3072 16B chunks, swizzle ch -> elem ch*8 + (ch>>6)*32
    {
        const uint4* src = (const uint4*)(xvT + (long)bb * 24576);
#pragma unroll
        for (int it = 0; it < 12; ++it) {
            int ch = tid + it * 256;
            *(uint4*)(xv_s + ch * 8 + (ch >> 6) * 32) = src[ch];
        }
    }
    __syncthreads();

    int setid = pg * 4 + wave;           // 0..23; set 23 idle (writes zeros)
    f32x4 acc[4];
#pragma unroll
    for (int t = 0; t < 4; ++t) acc[t] = (f32x4){0.f, 0.f, 0.f, 0.f};

    const int abase = (quad & 1) * 544 + col * 8;
    const int mcol  = col * 16;
    const int l16   = lane * 16;

    if (setid < 23) {
        int p0 = setid * SETLEN;
        int i = 0, rem = p0;
        while (rem >= NFIELD - 1 - i) { rem -= NFIELD - 1 - i; ++i; }
        int j = i + 1 + rem;

        const char* wp = combo + (long)p0 * 4608;
        Pkg A = load_pkg(wp, mcol, l16);
        Pkg B = load_pkg(wp + 4608, mcol, l16);

#pragma unroll 2
        for (int k = 0; k < SETLEN; k += 2) {
            PKGCOMP(A)
            A = load_pkg(wp + 2 * 4608, mcol, l16);   // used 2 iters later
            PKGCOMP(B)
            B = load_pkg(wp + 3 * 4608, mcol, l16);
            wp += 2 * 4608;
        }
    }

    // reduce each acc component over the 16 column-lanes within its quad group
#pragma unroll
    for (int m = 1; m < 16; m <<= 1) {
#pragma unroll
        for (int t = 0; t < 4; ++t) {
#pragma unroll
            for (int r = 0; r < 4; ++r) acc[t][r] += __shfl_xor(acc[t][r], m, 64);
        }
    }
    if (col == 0) {
#pragma unroll
        for (int t = 0; t < 4; ++t) {
            f32x4 o = acc[t];
            *(f32x4*)&partial[setid * BATCH + bb * 64 + t * 16 + quad * 4] = o;
        }
    }
}

__device__ __forceinline__ void do_finalize(int b,
        const float* __restrict__ wval, const float* __restrict__ consts,
        const float* __restrict__ partial, float* __restrict__ out) {
    float s = consts[0];
#pragma unroll
    for (int f = 0; f < NFIELD; ++f) s += wval[f * BATCH + b];
#pragma unroll
    for (int g = 0; g < NSETS; ++g) s += partial[g * BATCH + b];
    out[b] = 1.0f / (1.0f + expf(-s));
}

// ---------------- fused cooperative kernel (primary path) ------------------
// 768 blocks x 256 thr, 51KB LDS, launch_bounds(256,3) -> exactly 3 blk/CU x
// 256 CU = 768 co-resident, so cooperative validation passes. Repack work is
// redistributed onto blocks 0..277 (runs after each block's gather unit).
__global__ __launch_bounds__(256, 3) void ffm_fused(
        const int* __restrict__ inputs,
        const float* __restrict__ v,
        const float* __restrict__ w,
        const float* __restrict__ W1,
        const float* __restrict__ W2,
        const float* __restrict__ b1,
        const float* __restrict__ b2,
        const float* __restrict__ bsc,
        __hip_bfloat16* __restrict__ xvT,
        char* __restrict__ combo,
        float* __restrict__ wval,
        float* __restrict__ consts,
        float* __restrict__ partial,
        float* __restrict__ out) {
    // [field][half][row64][8] with +32 elem (64B) pad per 512-elem half-group
    __shared__ __align__(16) __hip_bfloat16 xv_s[24 * 1088];  // 51 KB

    cg::grid_group grid = cg::this_grid();
    const int tid = threadIdx.x;
    const int blk = blockIdx.x;

    // -------- phase 1: embedding gather + weight repack --------
    do_gather(blk, tid, inputs, v, w, xvT, wval);
    if (blk < PAIRS) {
        if (tid < 64) do_repack(blk, tid, W1, W2, b1, combo);
    } else if (blk == PAIRS) {
        do_padzero(tid, combo);          // zero 2 pad pairs (tail prefetch)
    } else if (blk == PAIRS + 1) {
        do_b2sum(tid, (float*)xv_s, b2, bsc, consts);  // red overlays xv_s
    }
    grid.sync();                         // xvT/combo/consts now grid-visible

    // -------- phase 2: MFMA main --------
    do_main(blk, tid, xv_s, xvT, combo, partial);
    grid.sync();                         // partial now grid-visible

    // -------- phase 3: finalize --------
    if (blk < BATCH / 256) do_finalize(blk * 256 + tid, wval, consts, partial, out);
}

// ---------------- split-path fallback (identical semantics) ----------------
__global__ void prep_all(const int* __restrict__ inputs,
                         const float* __restrict__ v,
                         const float* __restrict__ w,
                         const float* __restrict__ W1,
                         const float* __restrict__ W2,
                         const float* __restrict__ b1,
                         const float* __restrict__ b2,
                         const float* __restrict__ bsc,
                         __hip_bfloat16* __restrict__ xvT,
                         char* __restrict__ combo,
                         float* __restrict__ wval,
                         float* __restrict__ consts) {
    __shared__ float red[256];
    int blk = blockIdx.x;
    if (blk < 768) {
        do_gather(blk, threadIdx.x, inputs, v, w, xvT, wval);
    } else {
        int wb = blk - 768;                        // 0..68
        int t = wb * 256 + threadIdx.x;            // < 17664
        do_repack(t >> 6, t & 63, W1, W2, b1, combo);
        if (wb == 1) do_padzero(threadIdx.x, combo);
        if (wb == 0) do_b2sum(threadIdx.x, red, b2, bsc, consts);
    }
}

__global__ __launch_bounds__(256, 3) void ffm_main(
        const __hip_bfloat16* __restrict__ xvT,
        const char* __restrict__ combo,
        float* __restrict__ partial) {
    __shared__ __align__(16) __hip_bfloat16 xv_s[24 * 1088];  // 51 KB
    do_main(blockIdx.x, threadIdx.x, xv_s, xvT, combo, partial);
}

__global__ void finalize(const float* __restrict__ wval,
                         const float* __restrict__ consts,
                         const float* __restrict__ partial,
                         float* __restrict__ out) {
    do_finalize(blockIdx.x * 256 + threadIdx.x, wval, consts, partial, out);
}

extern "C" void kernel_launch(void* const* d_in, const int* in_sizes, int n_in,
                              void* d_out, int out_size, void* d_ws, size_t ws_size,
                              hipStream_t stream) {
    const int*   inputs = (const int*)d_in[0];
    const float* w      = (const float*)d_in[1];
    const float* v      = (const float*)d_in[2];
    const float* bsc    = (const float*)d_in[3];
    const float* W1     = (const float*)d_in[4];
    const float* b1     = (const float*)d_in[5];
    const float* W2     = (const float*)d_in[6];
    const float* b2     = (const float*)d_in[7];
    float* out = (float*)d_out;

    char* ws = (char*)d_ws;
    __hip_bfloat16* xvT = (__hip_bfloat16*)(ws + XVT_OFF);
    char*  combo   = ws + COMBO_OFF;
    float* partial = (float*)(ws + PART_OFF);
    float* wval    = (float*)(ws + WVAL_OFF);
    float* consts  = (float*)(ws + CONST_OFF);

    void* args[] = {(void*)&inputs, (void*)&v, (void*)&w, (void*)&W1,
                    (void*)&W2, (void*)&b1, (void*)&b2, (void*)&bsc,
                    (void*)&xvT, (void*)&combo, (void*)&wval, (void*)&consts,
                    (void*)&partial, (void*)&out};
    hipError_t err = hipLaunchCooperativeKernel(ffm_fused, dim3(768), dim3(256),
                                                args, 0u, stream);
    if (err != hipSuccess) {
        // fallback: proven 3-kernel path (worst case == previous baseline)
        prep_all<<<768 + 69, 256, 0, stream>>>(inputs, v, w, W1, W2, b1, b2, bsc,
                                               xvT, combo, wval, consts);
        ffm_main<<<NBB * 6, 256, 0, stream>>>(xvT, combo, partial);
        finalize<<<BATCH / 256, 256, 0, stream>>>(wval, consts, partial, out);
    }
}

// Round 2
// 192.449 us; speedup vs baseline: 1.6540x; 1.6540x over previous
//
#include <hip/hip_runtime.h>
#include <hip/hip_bf16.h>
#include <math.h>

#define BATCH   8192
#define NFIELD  24
#define FAC     16
#define PAIRS   276
#define NSETS   24             // 23 real 12-pair sets + 1 idle set
#define SETLEN  12
#define NBB     (BATCH / 64)   // 128 batch blocks of 64 rows

typedef __attribute__((ext_vector_type(8))) __bf16 bf16x8;
typedef __attribute__((ext_vector_type(4))) float f32x4;

// ---- workspace layout (bytes) ----
// xvT:   [128][24][2][64][8] bf16 = 6,291,456
// combo: [276 + 2 pad][4608]      = 1,281,024 (+pad)
// partial:[24][8192] f32          =   786,432
// wval:  [24][8192] f32           =   786,432
// consts: [1] f32; cnt: [128] int (zeroed by prep each iter — ws is poisoned)
#define XVT_OFF   0
#define COMBO_OFF 6291456
#define PART_OFF  (COMBO_OFF + 1285632)
#define WVAL_OFF  (PART_OFF + 786432)
#define CONST_OFF (WVAL_OFF + 786432)
#define CNT_OFF   (CONST_OFF + 256)

// ---------------- phase bodies ----------------

// One (field,b) gather unit: v-row -> bf16 xvT slab + linear term.
__device__ __forceinline__ void do_gather(int blk, int tid,
        const int* __restrict__ inputs, const float* __restrict__ v,
        const float* __restrict__ w,
        __hip_bfloat16* __restrict__ xvT, float* __restrict__ wval) {
    int t = blk * 256 + tid;                  // < 196608
    int field = t >> 13;
    int b = t & 8191;
    int idx = inputs[b * NFIELD + field];
    const float4* src = (const float4*)(v + (long)idx * FAC);
    union { __hip_bfloat16 h[16]; uint4 u[2]; } tmp;
    float4 a0 = src[0], a1 = src[1], a2 = src[2], a3 = src[3];
    tmp.h[0]  = __float2bfloat16(a0.x); tmp.h[1]  = __float2bfloat16(a0.y);
    tmp.h[2]  = __float2bfloat16(a0.z); tmp.h[3]  = __float2bfloat16(a0.w);
    tmp.h[4]  = __float2bfloat16(a1.x); tmp.h[5]  = __float2bfloat16(a1.y);
    tmp.h[6]  = __float2bfloat16(a1.z); tmp.h[7]  = __float2bfloat16(a1.w);
    tmp.h[8]  = __float2bfloat16(a2.x); tmp.h[9]  = __float2bfloat16(a2.y);
    tmp.h[10] = __float2bfloat16(a2.z); tmp.h[11] = __float2bfloat16(a2.w);
    tmp.h[12] = __float2bfloat16(a3.x); tmp.h[13] = __float2bfloat16(a3.y);
    tmp.h[14] = __float2bfloat16(a3.z); tmp.h[15] = __float2bfloat16(a3.w);
    int bb = b >> 6, row = b & 63;
    __hip_bfloat16* base = xvT + (long)bb * 24576 + field * 1024 + row * 8;
    *(uint4*)base         = tmp.u[0];
    *(uint4*)(base + 512) = tmp.u[1];
    wval[field * BATCH + b] = w[idx];
}

// One (pair p, lane-unit L in [0,64)) weight-repack unit.
__device__ __forceinline__ void do_repack(int p, int L,
        const float* __restrict__ W1, const float* __restrict__ W2,
        const float* __restrict__ b1, char* __restrict__ combo) {
    int q = L >> 4, c = L & 15;
    char* base = combo + (long)p * 4608;
    union { __hip_bfloat16 h[8]; uint4 u; } buf;
#pragma unroll
    for (int tt = 0; tt < 4; ++tt) {
#pragma unroll
        for (int jj = 0; jj < 8; ++jj)
            buf.h[jj] = __float2bfloat16(W1[p * 2048 + (q * 8 + jj) * 64 + tt * 16 + c]);
        *(uint4*)(base + 512 + tt * 1024 + L * 16) = buf.u;
    }
    if (L < 16) {
        float4 bv = {b1[p * 64 + L], b1[p * 64 + 16 + L], b1[p * 64 + 32 + L], b1[p * 64 + 48 + L]};
        *(float4*)(base + L * 16) = bv;
        float4 wv = {W2[p * 64 + L], W2[p * 64 + 16 + L], W2[p * 64 + 32 + L], W2[p * 64 + 48 + L]};
        *(float4*)(base + 256 + L * 16) = wv;
    }
}

__device__ __forceinline__ void do_padzero(int tid, char* __restrict__ combo) {
    uint4 z = {0, 0, 0, 0};
    for (int k = tid; k < 576; k += 256)
        *(uint4*)(combo + (long)PAIRS * 4608 + k * 16) = z;
}

// b2 sum + global bias -> consts[0].
__device__ __forceinline__ void do_b2sum(int tid, float* red,
        const float* __restrict__ b2, const float* __restrict__ bsc,
        float* __restrict__ consts) {
    float s = 0.f;
    for (int k = tid; k < PAIRS; k += 256) s += b2[k];
    red[tid] = s;
    __syncthreads();
    for (int off = 128; off > 0; off >>= 1) {
        if (tid < off) red[tid] += red[tid + off];
        __syncthreads();
    }
    if (tid == 0) consts[0] = red[0] + bsc[0];
}

// Fused prep: blocks [0,768) gather; blocks [768,837) repack weights,
// compute consts, and zero the per-bb completion counters (ws is re-poisoned
// between iterations, so cnt MUST be re-zeroed here every launch).
__global__ void prep_all(const int* __restrict__ inputs,
                         const float* __restrict__ v,
                         const float* __restrict__ w,
                         const float* __restrict__ W1,
                         const float* __restrict__ W2,
                         const float* __restrict__ b1,
                         const float* __restrict__ b2,
                         const float* __restrict__ bsc,
                         __hip_bfloat16* __restrict__ xvT,
                         char* __restrict__ combo,
                         float* __restrict__ wval,
                         float* __restrict__ consts,
                         int* __restrict__ cnt) {
    __shared__ float red[256];
    int blk = blockIdx.x;
    if (blk < 768) {
        do_gather(blk, threadIdx.x, inputs, v, w, xvT, wval);
    } else {
        int wb = blk - 768;                        // 0..68
        int t = wb * 256 + threadIdx.x;            // < 17664
        do_repack(t >> 6, t & 63, W1, W2, b1, combo);
        if (wb == 1) do_padzero(threadIdx.x, combo);
        if (wb == 2 && threadIdx.x < NBB) cnt[threadIdx.x] = 0;
        if (wb == 0) do_b2sum(threadIdx.x, red, b2, bsc, consts);
    }
}

// One pair's weight package in registers. Bias pre-broadcast into persistent
// MFMA C-operands (D!=C, so cb survives and is reused across all 4 row-tiles).
struct Pkg {
    f32x4 cb0, cb1, cb2, cb3;
    float4 mw;
    bf16x8 f0, f1, f2, f3;
};

__device__ __forceinline__ Pkg load_pkg(const char* p, int mcol, int l16) {
    Pkg k;
    float4 tb = *(const float4*)(p + mcol);
    k.cb0 = (f32x4){tb.x, tb.x, tb.x, tb.x};
    k.cb1 = (f32x4){tb.y, tb.y, tb.y, tb.y};
    k.cb2 = (f32x4){tb.z, tb.z, tb.z, tb.z};
    k.cb3 = (f32x4){tb.w, tb.w, tb.w, tb.w};
    k.mw = *(const float4*)(p + 256 + mcol);
    k.f0 = *(const bf16x8*)(p + 512  + l16);
    k.f1 = *(const bf16x8*)(p + 1536 + l16);
    k.f2 = *(const bf16x8*)(p + 2560 + l16);
    k.f3 = *(const bf16x8*)(p + 3584 + l16);
    return k;
}

// Apply one package to all 4 row-tiles. Packed-f32 epilogue (v_pk_max/v_pk_fma).
#define PKGCOMP(P)                                                            \
    {                                                                         \
        int fso = ((quad < 2) ? i : j) * 1088;                                \
        const f32x4 z4 = {0.f, 0.f, 0.f, 0.f};                                \
        _Pragma("unroll")                                                     \
        for (int t = 0; t < 4; ++t) {                                         \
            bf16x8 af = *(const bf16x8*)(xv_s + fso + abase + t * 128);       \
            f32x4 c0 = __builtin_amdgcn_mfma_f32_16x16x32_bf16(af, P.f0, P.cb0, 0, 0, 0); \
            f32x4 c1 = __builtin_amdgcn_mfma_f32_16x16x32_bf16(af, P.f1, P.cb1, 0, 0, 0); \
            f32x4 c2 = __builtin_amdgcn_mfma_f32_16x16x32_bf16(af, P.f2, P.cb2, 0, 0, 0); \
            f32x4 c3 = __builtin_amdgcn_mfma_f32_16x16x32_bf16(af, P.f3, P.cb3, 0, 0, 0); \
            acc[t] = acc[t] + __builtin_elementwise_max(c0, z4) * P.mw.x;     \
            acc[t] = acc[t] + __builtin_elementwise_max(c1, z4) * P.mw.y;     \
            acc[t] = acc[t] + __builtin_elementwise_max(c2, z4) * P.mw.z;     \
            acc[t] = acc[t] + __builtin_elementwise_max(c3, z4) * P.mw.w;     \
        }                                                                     \
        ++j;                                                                  \
        if (j == NFIELD) { ++i; j = i + 1; }                                  \
    }

// MFMA main phase: one 64-row slab in LDS shared by 4 waves; each wave owns a
// distinct 12-pair set, barrier-free K-loop, depth-2 two-set register prefetch.
__device__ __forceinline__ void do_main(int blk, int tid,
        __hip_bfloat16* xv_s,
        const __hip_bfloat16* __restrict__ xvT,
        const char* __restrict__ combo,
        float* __restrict__ partial) {
    int bb   = blk & (NBB - 1);
    int pg   = blk >> 7;                 // 0..5
    int lane = tid & 63;
    int wave = tid >> 6;
    int col  = lane & 15;
    int quad = lane >> 4;

    // stage 48KB slab: 3072 16B chunks, swizzle ch -> elem ch*8 + (ch>>6)*32
    {
        const uint4* src = (const uint4*)(xvT + (long)bb * 24576);
#pragma unroll
        for (int it = 0; it < 12; ++it) {
            int ch = tid + it * 256;
            *(uint4*)(xv_s + ch * 8 + (ch >> 6) * 32) = src[ch];
        }
    }
    __syncthreads();

    int setid = pg * 4 + wave;           // 0..23; set 23 idle (writes zeros)
    f32x4 acc[4];
#pragma unroll
    for (int t = 0; t < 4; ++t) acc[t] = (f32x4){0.f, 0.f, 0.f, 0.f};

    const int abase = (quad & 1) * 544 + col * 8;
    const int mcol  = col * 16;
    const int l16   = lane * 16;

    if (setid < 23) {
        int p0 = setid * SETLEN;
        int i = 0, rem = p0;
        while (rem >= NFIELD - 1 - i) { rem -= NFIELD - 1 - i; ++i; }
        int j = i + 1 + rem;

        const char* wp = combo + (long)p0 * 4608;
        Pkg A = load_pkg(wp, mcol, l16);
        Pkg B = load_pkg(wp + 4608, mcol, l16);

#pragma unroll 2
        for (int k = 0; k < SETLEN; k += 2) {
            PKGCOMP(A)
            A = load_pkg(wp + 2 * 4608, mcol, l16);   // used 2 iters later
            PKGCOMP(B)
            B = load_pkg(wp + 3 * 4608, mcol, l16);
            wp += 2 * 4608;
        }
    }

    // reduce each acc component over the 16 column-lanes within its quad group
#pragma unroll
    for (int m = 1; m < 16; m <<= 1) {
#pragma unroll
        for (int t = 0; t < 4; ++t) {
#pragma unroll
            for (int r = 0; r < 4; ++r) acc[t][r] += __shfl_xor(acc[t][r], m, 64);
        }
    }
    if (col == 0) {
#pragma unroll
        for (int t = 0; t < 4; ++t) {
            f32x4 o = acc[t];
            *(f32x4*)&partial[setid * BATCH + bb * 64 + t * 16 + quad * 4] = o;
        }
    }
}

// Main kernel with fused finalize: the LAST of the 6 blocks sharing a bb
// (detected via device-scope per-bb counter; no waiting, no co-residency
// assumption, no deadlock risk) computes the 64 output rows. Release side:
// every wave fences its partial stores (__threadfence = agent-scope wb)
// before block rep bumps the counter; acquire side: winner fences (inv)
// before reading other blocks' partials across XCDs.
__global__ __launch_bounds__(256, 3) void ffm_main(
        const __hip_bfloat16* __restrict__ xvT,
        const char* __restrict__ combo,
        const float* __restrict__ wval,
        const float* __restrict__ consts,
        float* __restrict__ partial,
        int* __restrict__ cnt,
        float* __restrict__ out) {
    __shared__ __align__(16) __hip_bfloat16 xv_s[24 * 1088];  // 51 KB
    __shared__ int win_s;

    int tid = threadIdx.x;
    int bb  = blockIdx.x & (NBB - 1);

    do_main(blockIdx.x, tid, xv_s, xvT, combo, partial);

    __threadfence();                     // release this wave's partial stores
    __syncthreads();                     // all 4 waves fenced
    if (tid == 0) win_s = (atomicAdd(&cnt[bb], 1) == 5);
    __syncthreads();
    if (win_s) {
        __threadfence();                 // acquire: see other XCDs' partials
        float* red = (float*)xv_s;       // xv_s no longer needed: reuse
        int r = tid & 63, grp = tid >> 6;   // 4 groups x 6 {fields,sets} each
        int base = bb * 64 + r;
        float s = 0.f;
#pragma unroll
        for (int k = 0; k < 6; ++k) s += wval[(grp * 6 + k) * BATCH + base];
#pragma unroll
        for (int k = 0; k < 6; ++k) s += partial[(grp * 6 + k) * BATCH + base];
        red[grp * 64 + r] = s;
        __syncthreads();
        if (tid < 64) {
            float t2 = consts[0] + red[tid] + red[64 + tid] + red[128 + tid] + red[192 + tid];
            out[bb * 64 + tid] = 1.0f / (1.0f + expf(-t2));
        }
    }
}

extern "C" void kernel_launch(void* const* d_in, const int* in_sizes, int n_in,
                              void* d_out, int out_size, void* d_ws, size_t ws_size,
                              hipStream_t stream) {
    const int*   inputs = (const int*)d_in[0];
    const float* w      = (const float*)d_in[1];
    const float* v      = (const float*)d_in[2];
    const float* bsc    = (const float*)d_in[3];
    const float* W1     = (const float*)d_in[4];
    const float* b1     = (const float*)d_in[5];
    const float* W2     = (const float*)d_in[6];
    const float* b2     = (const float*)d_in[7];
    float* out = (float*)d_out;

    char* ws = (char*)d_ws;
    __hip_bfloat16* xvT = (__hip_bfloat16*)(ws + XVT_OFF);
    char*  combo   = ws + COMBO_OFF;
    float* partial = (float*)(ws + PART_OFF);
    float* wval    = (float*)(ws + WVAL_OFF);
    float* consts  = (float*)(ws + CONST_OFF);
    int*   cnt     = (int*)(ws + CNT_OFF);

    prep_all<<<768 + 69, 256, 0, stream>>>(inputs, v, w, W1, W2, b1, b2, bsc,
                                           xvT, combo, wval, consts, cnt);
    ffm_main<<<NBB * 6, 256, 0, stream>>>(xvT, combo, wval, consts,
                                          partial, cnt, out);
}

// Round 3
// 141.377 us; speedup vs baseline: 2.2515x; 1.3612x over previous
//
#include <hip/hip_runtime.h>
#include <hip/hip_bf16.h>
#include <math.h>

#define BATCH   8192
#define NFIELD  24
#define FAC     16
#define PAIRS   276
#define NSETS   24             // 23 real 12-pair sets + 1 idle set
#define SETLEN  12
#define NBB     (BATCH / 64)   // 128 batch blocks of 64 rows

typedef __attribute__((ext_vector_type(8))) __bf16 bf16x8;
typedef __attribute__((ext_vector_type(4))) float f32x4;

// ---- workspace layout (bytes) ----
// combo:  [276 + 2 pad][4608]      = 1,281,024 (+pad)
// partial:[24][8192] f32           =   786,432
// wsum:   [8192] f32               =    32,768
// consts: [1] f32
// (xvT eliminated: the gather now lands directly in ffm_main's LDS)
#define COMBO_OFF 0
#define PART_OFF  1285632
#define WSUM_OFF  (PART_OFF + 786432)
#define CONST_OFF (WSUM_OFF + 32768)

// ---------------- prep: weight repack only (69 blocks) ----------------

// One (pair p, lane-unit L in [0,64)) weight-repack unit.
__device__ __forceinline__ void do_repack(int p, int L,
        const float* __restrict__ W1, const float* __restrict__ W2,
        const float* __restrict__ b1, char* __restrict__ combo) {
    int q = L >> 4, c = L & 15;
    char* base = combo + (long)p * 4608;
    union { __hip_bfloat16 h[8]; uint4 u; } buf;
#pragma unroll
    for (int tt = 0; tt < 4; ++tt) {
#pragma unroll
        for (int jj = 0; jj < 8; ++jj)
            buf.h[jj] = __float2bfloat16(W1[p * 2048 + (q * 8 + jj) * 64 + tt * 16 + c]);
        *(uint4*)(base + 512 + tt * 1024 + L * 16) = buf.u;
    }
    if (L < 16) {
        float4 bv = {b1[p * 64 + L], b1[p * 64 + 16 + L], b1[p * 64 + 32 + L], b1[p * 64 + 48 + L]};
        *(float4*)(base + L * 16) = bv;
        float4 wv = {W2[p * 64 + L], W2[p * 64 + 16 + L], W2[p * 64 + 32 + L], W2[p * 64 + 48 + L]};
        *(float4*)(base + 256 + L * 16) = wv;
    }
}

__global__ void prep_w(const float* __restrict__ W1,
                       const float* __restrict__ W2,
                       const float* __restrict__ b1,
                       const float* __restrict__ b2,
                       const float* __restrict__ bsc,
                       char* __restrict__ combo,
                       float* __restrict__ consts) {
    __shared__ float red[256];
    int blk = blockIdx.x;                       // 0..68
    int t = blk * 256 + threadIdx.x;            // < 17664 = 276*64
    do_repack(t >> 6, t & 63, W1, W2, b1, combo);
    if (blk == 1) {                             // zero the 2 pad pairs
        uint4 z = {0, 0, 0, 0};
        for (int k = threadIdx.x; k < 576; k += 256)
            *(uint4*)(combo + (long)PAIRS * 4608 + k * 16) = z;
    }
    if (blk == 0) {                             // b2 sum + global bias
        float s = 0.f;
        for (int k = threadIdx.x; k < PAIRS; k += 256) s += b2[k];
        red[threadIdx.x] = s;
        __syncthreads();
        for (int off = 128; off > 0; off >>= 1) {
            if (threadIdx.x < off) red[threadIdx.x] += red[threadIdx.x + off];
            __syncthreads();
        }
        if (threadIdx.x == 0) consts[0] = red[0] + bsc[0];
    }
}

// ---------------- main ----------------

// One pair's weight package in registers. Bias pre-broadcast into persistent
// MFMA C-operands (D!=C, so cb survives and is reused across all 4 row-tiles).
struct Pkg {
    f32x4 cb0, cb1, cb2, cb3;
    float4 mw;
    bf16x8 f0, f1, f2, f3;
};

__device__ __forceinline__ Pkg load_pkg(const char* p, int mcol, int l16) {
    Pkg k;
    float4 tb = *(const float4*)(p + mcol);
    k.cb0 = (f32x4){tb.x, tb.x, tb.x, tb.x};
    k.cb1 = (f32x4){tb.y, tb.y, tb.y, tb.y};
    k.cb2 = (f32x4){tb.z, tb.z, tb.z, tb.z};
    k.cb3 = (f32x4){tb.w, tb.w, tb.w, tb.w};
    k.mw = *(const float4*)(p + 256 + mcol);
    k.f0 = *(const bf16x8*)(p + 512  + l16);
    k.f1 = *(const bf16x8*)(p + 1536 + l16);
    k.f2 = *(const bf16x8*)(p + 2560 + l16);
    k.f3 = *(const bf16x8*)(p + 3584 + l16);
    return k;
}

// Apply one package to all 4 row-tiles. Packed-f32 epilogue (v_pk_max/v_pk_fma).
#define PKGCOMP(P)                                                            \
    {                                                                         \
        int fso = ((quad < 2) ? i : j) * 1088;                                \
        const f32x4 z4 = {0.f, 0.f, 0.f, 0.f};                                \
        _Pragma("unroll")                                                     \
        for (int t = 0; t < 4; ++t) {                                         \
            bf16x8 af = *(const bf16x8*)(xv_s + fso + abase + t * 128);       \
            f32x4 c0 = __builtin_amdgcn_mfma_f32_16x16x32_bf16(af, P.f0, P.cb0, 0, 0, 0); \
            f32x4 c1 = __builtin_amdgcn_mfma_f32_16x16x32_bf16(af, P.f1, P.cb1, 0, 0, 0); \
            f32x4 c2 = __builtin_amdgcn_mfma_f32_16x16x32_bf16(af, P.f2, P.cb2, 0, 0, 0); \
            f32x4 c3 = __builtin_amdgcn_mfma_f32_16x16x32_bf16(af, P.f3, P.cb3, 0, 0, 0); \
            acc[t] = acc[t] + __builtin_elementwise_max(c0, z4) * P.mw.x;     \
            acc[t] = acc[t] + __builtin_elementwise_max(c1, z4) * P.mw.y;     \
            acc[t] = acc[t] + __builtin_elementwise_max(c2, z4) * P.mw.z;     \
            acc[t] = acc[t] + __builtin_elementwise_max(c3, z4) * P.mw.w;     \
        }                                                                     \
        ++j;                                                                  \
        if (j == NFIELD) { ++i; j = i + 1; }                                  \
    }

// 256-thread blocks; the block gathers its own 64-row slab of v-embeddings
// straight into LDS (no xvT global round-trip: the 6 blocks sharing bb are
// 128 apart => same XCD => one HBM fetch + 5 L2 hits per v-row). 4 waves
// own distinct 12-pair sets; barrier-free K-loop, depth-2 register prefetch
// issued BEFORE the gather so pkg latency hides under staging.
__global__ __launch_bounds__(256, 3) void ffm_main(
        const int*   __restrict__ inputs,
        const float* __restrict__ v,
        const float* __restrict__ w,
        const char*  __restrict__ combo,
        float* __restrict__ wsum,
        float* __restrict__ partial) {
    // [field][half][row64][8] with +32 elem (64B) pad per 512-elem half-group
    __shared__ __align__(16) __hip_bfloat16 xv_s[24 * 1088];  // 51 KB
    __shared__ float wred[256];                               // +1 KB

    int tid  = threadIdx.x;
    int bb   = blockIdx.x & (NBB - 1);
    int pg   = blockIdx.x >> 7;          // 0..5
    int lane = tid & 63;
    int wave = tid >> 6;
    int col  = lane & 15;
    int quad = lane >> 4;

    const int abase = (quad & 1) * 544 + col * 8;   // + t*128 per row-tile
    const int mcol  = col * 16;
    const int l16   = lane * 16;

    // ---- issue weight-package prefetch first (independent of gather) ----
    int setid = pg * 4 + wave;           // 0..23; set 23 idle (writes zeros)
    int i = 0, j = 1;
    const char* wp = combo;
    Pkg A, B;
    bool active = (setid < 23);
    if (active) {
        int p0 = setid * SETLEN;
        int rem = p0;
        i = 0;
        while (rem >= NFIELD - 1 - i) { rem -= NFIELD - 1 - i; ++i; }
        j = i + 1 + rem;
        wp = combo + (long)p0 * 4608;
        A = load_pkg(wp, mcol, l16);
        B = load_pkg(wp + 4608, mcol, l16);
    }

    // ---- gather 64 rows x 24 fields of v directly into LDS ----
    // unit u = field*64 + row: consecutive lanes -> consecutive rows -> 16B
    // LDS-write stride -> conflict-free ds_write_b128.
    {
        int row = tid & 63;              // fixed per thread (256 % 64 == 0)
        float ws_acc = 0.f;
#pragma unroll
        for (int k2 = 0; k2 < 6; ++k2) {
            int u = k2 * 256 + tid;
            int field = u >> 6;          // uniform per wave per k2
            int idx = inputs[(bb * 64 + row) * NFIELD + field];
            const float4* src = (const float4*)(v + (long)idx * FAC);
            union { __hip_bfloat16 h[16]; uint4 uu[2]; } tmp;
            float4 a0 = src[0], a1 = src[1], a2 = src[2], a3 = src[3];
            tmp.h[0]  = __float2bfloat16(a0.x); tmp.h[1]  = __float2bfloat16(a0.y);
            tmp.h[2]  = __float2bfloat16(a0.z); tmp.h[3]  = __float2bfloat16(a0.w);
            tmp.h[4]  = __float2bfloat16(a1.x); tmp.h[5]  = __float2bfloat16(a1.y);
            tmp.h[6]  = __float2bfloat16(a1.z); tmp.h[7]  = __float2bfloat16(a1.w);
            tmp.h[8]  = __float2bfloat16(a2.x); tmp.h[9]  = __float2bfloat16(a2.y);
            tmp.h[10] = __float2bfloat16(a2.z); tmp.h[11] = __float2bfloat16(a2.w);
            tmp.h[12] = __float2bfloat16(a3.x); tmp.h[13] = __float2bfloat16(a3.y);
            tmp.h[14] = __float2bfloat16(a3.z); tmp.h[15] = __float2bfloat16(a3.w);
            __hip_bfloat16* dst = xv_s + field * 1088 + row * 8;
            *(uint4*)dst         = tmp.uu[0];
            *(uint4*)(dst + 544) = tmp.uu[1];
            if (pg == 0) ws_acc += w[idx];   // linear term (pg==0 blocks only)
        }
        if (pg == 0) wred[tid] = ws_acc;
    }
    __syncthreads();

    if (pg == 0 && tid < 64) {
        wsum[bb * 64 + tid] = wred[tid] + wred[64 + tid] + wred[128 + tid] + wred[192 + tid];
    }

    f32x4 acc[4];
#pragma unroll
    for (int t = 0; t < 4; ++t) acc[t] = (f32x4){0.f, 0.f, 0.f, 0.f};

    if (active) {
#pragma unroll 2
        for (int k = 0; k < SETLEN; k += 2) {
            PKGCOMP(A)
            A = load_pkg(wp + 2 * 4608, mcol, l16);   // used 2 iters later
            PKGCOMP(B)
            B = load_pkg(wp + 3 * 4608, mcol, l16);
            wp += 2 * 4608;
        }
    }

    // reduce each acc component over the 16 column-lanes within its quad group
#pragma unroll
    for (int m = 1; m < 16; m <<= 1) {
#pragma unroll
        for (int t = 0; t < 4; ++t) {
#pragma unroll
            for (int r = 0; r < 4; ++r) acc[t][r] += __shfl_xor(acc[t][r], m, 64);
        }
    }
    if (col == 0) {
#pragma unroll
        for (int t = 0; t < 4; ++t) {
            f32x4 o = acc[t];
            *(f32x4*)&partial[setid * BATCH + bb * 64 + t * 16 + quad * 4] = o;
        }
    }
}

// Per-row finalize: 26 mutually-independent coalesced loads per thread.
__global__ void finalize(const float* __restrict__ wsum,
                         const float* __restrict__ consts,
                         const float* __restrict__ partial,
                         float* __restrict__ out) {
    int b = blockIdx.x * 256 + threadIdx.x;   // < 8192
    float s = consts[0] + wsum[b];
#pragma unroll
    for (int g = 0; g < NSETS; ++g) s += partial[g * BATCH + b];
    out[b] = 1.0f / (1.0f + expf(-s));
}

extern "C" void kernel_launch(void* const* d_in, const int* in_sizes, int n_in,
                              void* d_out, int out_size, void* d_ws, size_t ws_size,
                              hipStream_t stream) {
    const int*   inputs = (const int*)d_in[0];
    const float* w      = (const float*)d_in[1];
    const float* v      = (const float*)d_in[2];
    const float* bsc    = (const float*)d_in[3];
    const float* W1     = (const float*)d_in[4];
    const float* b1     = (const float*)d_in[5];
    const float* W2     = (const float*)d_in[6];
    const float* b2     = (const float*)d_in[7];
    float* out = (float*)d_out;

    char* ws = (char*)d_ws;
    char*  combo   = ws + COMBO_OFF;
    float* partial = (float*)(ws + PART_OFF);
    float* wsum    = (float*)(ws + WSUM_OFF);
    float* consts  = (float*)(ws + CONST_OFF);

    prep_w<<<69, 256, 0, stream>>>(W1, W2, b1, b2, bsc, combo, consts);
    ffm_main<<<NBB * 6, 256, 0, stream>>>(inputs, v, w, combo, wsum, partial);
    finalize<<<BATCH / 256, 256, 0, stream>>>(wsum, consts, partial, out);
}

// Round 4
// 136.061 us; speedup vs baseline: 2.3395x; 1.0391x over previous
//
#include <hip/hip_runtime.h>
#include <hip/hip_bf16.h>
#include <math.h>

#define BATCH   8192
#define NFIELD  24
#define FAC     16
#define PAIRS   276
#define NSETS   24             // 23 real 12-pair sets + 1 idle set
#define SETLEN  12
#define NBB     (BATCH / 64)   // 128 batch blocks of 64 rows

typedef __attribute__((ext_vector_type(8))) __bf16 bf16x8;
typedef __attribute__((ext_vector_type(4))) float f32x4;

// ---- workspace layout (bytes) ----
// xvT:   [128][24][2][64][8] bf16 = 6,291,456
// combo: [276 + 2 pad][4608]      = 1,281,024 (+pad)
// partial:[24][8192] f32          =   786,432
// wval:  [24][8192] f32           =   786,432
// consts: [1] f32
#define XVT_OFF   0
#define COMBO_OFF 6291456
#define PART_OFF  (COMBO_OFF + 1285632)
#define WVAL_OFF  (PART_OFF + 786432)
#define CONST_OFF (WVAL_OFF + 786432)

// Fused prep: blocks [0,768) gather v->xvT (+ w linear term -> wval);
// blocks [768,837) repack weights.
__global__ void prep_all(const int* __restrict__ inputs,
                         const float* __restrict__ v,
                         const float* __restrict__ w,
                         const float* __restrict__ W1,
                         const float* __restrict__ W2,
                         const float* __restrict__ b1,
                         const float* __restrict__ b2,
                         const float* __restrict__ bsc,
                         __hip_bfloat16* __restrict__ xvT,
                         char* __restrict__ combo,
                         float* __restrict__ wval,
                         float* __restrict__ consts) {
    __shared__ float red[256];
    int blk = blockIdx.x;
    if (blk < 768) {
        int t = blk * 256 + threadIdx.x;          // < 196608
        int field = t >> 13;
        int b = t & 8191;
        int idx = inputs[b * NFIELD + field];
        const float4* src = (const float4*)(v + (long)idx * FAC);
        union { __hip_bfloat16 h[16]; uint4 u[2]; } tmp;
        float4 a0 = src[0], a1 = src[1], a2 = src[2], a3 = src[3];
        tmp.h[0]  = __float2bfloat16(a0.x); tmp.h[1]  = __float2bfloat16(a0.y);
        tmp.h[2]  = __float2bfloat16(a0.z); tmp.h[3]  = __float2bfloat16(a0.w);
        tmp.h[4]  = __float2bfloat16(a1.x); tmp.h[5]  = __float2bfloat16(a1.y);
        tmp.h[6]  = __float2bfloat16(a1.z); tmp.h[7]  = __float2bfloat16(a1.w);
        tmp.h[8]  = __float2bfloat16(a2.x); tmp.h[9]  = __float2bfloat16(a2.y);
        tmp.h[10] = __float2bfloat16(a2.z); tmp.h[11] = __float2bfloat16(a2.w);
        tmp.h[12] = __float2bfloat16(a3.x); tmp.h[13] = __float2bfloat16(a3.y);
        tmp.h[14] = __float2bfloat16(a3.z); tmp.h[15] = __float2bfloat16(a3.w);
        int bb = b >> 6, row = b & 63;
        __hip_bfloat16* base = xvT + (long)bb * 24576 + field * 1024 + row * 8;
        *(uint4*)base         = tmp.u[0];
        *(uint4*)(base + 512) = tmp.u[1];
        // linear-term gather, coalesced write (read by finalize)
        wval[field * BATCH + b] = w[idx];
    } else {
        int wb = blk - 768;                        // 0..68
        int t = wb * 256 + threadIdx.x;            // < 17664
        int p = t >> 6;
        int L = t & 63;
        int q = L >> 4, c = L & 15;
        char* base = combo + (long)p * 4608;
        union { __hip_bfloat16 h[8]; uint4 u; } buf;
#pragma unroll
        for (int tt = 0; tt < 4; ++tt) {
#pragma unroll
            for (int jj = 0; jj < 8; ++jj)
                buf.h[jj] = __float2bfloat16(W1[p * 2048 + (q * 8 + jj) * 64 + tt * 16 + c]);
            *(uint4*)(base + 512 + tt * 1024 + L * 16) = buf.u;
        }
        if (L < 16) {
            float4 bv = {b1[p * 64 + L], b1[p * 64 + 16 + L], b1[p * 64 + 32 + L], b1[p * 64 + 48 + L]};
            *(float4*)(base + L * 16) = bv;
            float4 wv = {W2[p * 64 + L], W2[p * 64 + 16 + L], W2[p * 64 + 32 + L], W2[p * 64 + 48 + L]};
            *(float4*)(base + 256 + L * 16) = wv;
        }
        if (wb == 1) {   // zero the 2 pad pairs (depth-2 tail prefetch reads them)
            uint4 z = {0, 0, 0, 0};
            for (int k = threadIdx.x; k < 576; k += 256)
                *(uint4*)(combo + (long)PAIRS * 4608 + k * 16) = z;
        }
        if (wb == 0) {
            float s = 0.f;
            for (int k = threadIdx.x; k < PAIRS; k += 256) s += b2[k];
            red[threadIdx.x] = s;
            __syncthreads();
            for (int off = 128; off > 0; off >>= 1) {
                if (threadIdx.x < off) red[threadIdx.x] += red[threadIdx.x + off];
                __syncthreads();
            }
            if (threadIdx.x == 0) consts[0] = red[0] + bsc[0];
        }
    }
}

// One pair's weight package in registers. Bias pre-broadcast into persistent
// MFMA C-operands (D!=C, so cb survives and is reused across all 4 row-tiles).
struct Pkg {
    f32x4 cb0, cb1, cb2, cb3;
    float4 mw;
    bf16x8 f0, f1, f2, f3;
};

__device__ __forceinline__ Pkg load_pkg(const char* p, int mcol, int l16) {
    Pkg k;
    float4 tb = *(const float4*)(p + mcol);
    k.cb0 = (f32x4){tb.x, tb.x, tb.x, tb.x};
    k.cb1 = (f32x4){tb.y, tb.y, tb.y, tb.y};
    k.cb2 = (f32x4){tb.z, tb.z, tb.z, tb.z};
    k.cb3 = (f32x4){tb.w, tb.w, tb.w, tb.w};
    k.mw = *(const float4*)(p + 256 + mcol);
    k.f0 = *(const bf16x8*)(p + 512  + l16);
    k.f1 = *(const bf16x8*)(p + 1536 + l16);
    k.f2 = *(const bf16x8*)(p + 2560 + l16);
    k.f3 = *(const bf16x8*)(p + 3584 + l16);
    return k;
}

// Apply one package to all 4 row-tiles. Packed-f32 epilogue (v_pk_max/v_pk_fma).
#define PKGCOMP(P)                                                            \
    {                                                                         \
        int fso = ((quad < 2) ? i : j) * 1088;                                \
        const f32x4 z4 = {0.f, 0.f, 0.f, 0.f};                                \
        _Pragma("unroll")                                                     \
        for (int t = 0; t < 4; ++t) {                                         \
            bf16x8 af = *(const bf16x8*)(xv_s + fso + abase + t * 128);       \
            f32x4 c0 = __builtin_amdgcn_mfma_f32_16x16x32_bf16(af, P.f0, P.cb0, 0, 0, 0); \
            f32x4 c1 = __builtin_amdgcn_mfma_f32_16x16x32_bf16(af, P.f1, P.cb1, 0, 0, 0); \
            f32x4 c2 = __builtin_amdgcn_mfma_f32_16x16x32_bf16(af, P.f2, P.cb2, 0, 0, 0); \
            f32x4 c3 = __builtin_amdgcn_mfma_f32_16x16x32_bf16(af, P.f3, P.cb3, 0, 0, 0); \
            acc[t] = acc[t] + __builtin_elementwise_max(c0, z4) * P.mw.x;     \
            acc[t] = acc[t] + __builtin_elementwise_max(c1, z4) * P.mw.y;     \
            acc[t] = acc[t] + __builtin_elementwise_max(c2, z4) * P.mw.z;     \
            acc[t] = acc[t] + __builtin_elementwise_max(c3, z4) * P.mw.w;     \
        }                                                                     \
        ++j;                                                                  \
        if (j == NFIELD) { ++i; j = i + 1; }                                  \
    }

// 256-thread blocks, one 64-row slab in LDS shared by 4 waves; each wave owns
// a distinct 12-pair set (setid = pg*4+wave), applies each package to 4 row
// tiles. Barrier-free K-loop, depth-2 two-set register prefetch.
// Stage path: global_load_lds (HBM->LDS DMA, no VGPR round-trip); the swizzle
// dst_byte = ch*16 + (ch>>6)*64 is wave-linear (ch>>6 = it*4+wave const per
// wave), satisfying the wave-uniform-base + lane*16 HW requirement.
__global__ __launch_bounds__(256, 3) void ffm_main(
        const __hip_bfloat16* __restrict__ xvT,
        const char* __restrict__ combo,
        float* __restrict__ partial) {
    // [field][half][row64][8] with +32 elem (64B) pad per 512-elem half-group
    __shared__ __align__(16) __hip_bfloat16 xv_s[24 * 1088];  // 51 KB

    int tid  = threadIdx.x;
    int bb   = blockIdx.x & (NBB - 1);
    int pg   = blockIdx.x >> 7;          // 0..5
    int lane = tid & 63;
    int wave = tid >> 6;
    int col  = lane & 15;
    int quad = lane >> 4;

    const int abase = (quad & 1) * 544 + col * 8;   // + t*128 per row-tile
    const int mcol  = col * 16;
    const int l16   = lane * 16;

    // ---- issue weight-package prefetch first (overlaps the stage DMA) ----
    int setid = pg * 4 + wave;           // 0..23; set 23 idle (writes zeros)
    int i = 0, j = 1;
    const char* wp = combo;
    Pkg A, B;
    bool active = (setid < 23);
    if (active) {
        int p0 = setid * SETLEN;
        int rem = p0;
        while (rem >= NFIELD - 1 - i) { rem -= NFIELD - 1 - i; ++i; }
        j = i + 1 + rem;
        wp = combo + (long)p0 * 4608;
        A = load_pkg(wp, mcol, l16);
        B = load_pkg(wp + 4608, mcol, l16);
    }

    // ---- stage 48KB slab: 3072 16B chunks, swizzled ----
    {
        const char* srcb = (const char*)(xvT + (long)bb * 24576);
#if __has_builtin(__builtin_amdgcn_global_load_lds)
#pragma unroll
        for (int it = 0; it < 12; ++it) {
            int ch0 = it * 256 + wave * 64;                   // wave-uniform
            char* ldst = (char*)xv_s + ch0 * 16 + (it * 4 + wave) * 64;
            const char* g = srcb + (long)(ch0 + lane) * 16;
            __builtin_amdgcn_global_load_lds(
                (const __attribute__((address_space(1))) unsigned int*)g,
                (__attribute__((address_space(3))) unsigned int*)ldst,
                16, 0, 0);
        }
#else
        const uint4* src = (const uint4*)srcb;
#pragma unroll
        for (int it = 0; it < 12; ++it) {
            int ch = tid + it * 256;
            *(uint4*)(xv_s + ch * 8 + (ch >> 6) * 32) = src[ch];
        }
#endif
    }
    __syncthreads();   // compiler drains vmcnt (incl. global_load_lds) here

    f32x4 acc[4];
#pragma unroll
    for (int t = 0; t < 4; ++t) acc[t] = (f32x4){0.f, 0.f, 0.f, 0.f};

    if (active) {
#pragma unroll 2
        for (int k = 0; k < SETLEN; k += 2) {
            PKGCOMP(A)
            A = load_pkg(wp + 2 * 4608, mcol, l16);   // used 2 iters later
            PKGCOMP(B)
            B = load_pkg(wp + 3 * 4608, mcol, l16);
            wp += 2 * 4608;
        }
    }

    // reduce each acc component over the 16 column-lanes within its quad group
#pragma unroll
    for (int m = 1; m < 16; m <<= 1) {
#pragma unroll
        for (int t = 0; t < 4; ++t) {
#pragma unroll
            for (int r = 0; r < 4; ++r) acc[t][r] += __shfl_xor(acc[t][r], m, 64);
        }
    }
    if (col == 0) {
#pragma unroll
        for (int t = 0; t < 4; ++t) {
            f32x4 o = acc[t];
            *(f32x4*)&partial[setid * BATCH + bb * 64 + t * 16 + quad * 4] = o;
        }
    }
}

// Per-row finalize. All 48 loads are coalesced across threads (stride-BATCH
// columns) and mutually independent, so they overlap into ~2 memory round trips.
__global__ void finalize(const float* __restrict__ wval,
                         const float* __restrict__ consts,
                         const float* __restrict__ partial,
                         float* __restrict__ out) {
    int b = blockIdx.x * 256 + threadIdx.x;   // < 8192
    float s = consts[0];
#pragma unroll
    for (int f = 0; f < NFIELD; ++f) s += wval[f * BATCH + b];
#pragma unroll
    for (int g = 0; g < NSETS; ++g) s += partial[g * BATCH + b];
    out[b] = 1.0f / (1.0f + expf(-s));
}

extern "C" void kernel_launch(void* const* d_in, const int* in_sizes, int n_in,
                              void* d_out, int out_size, void* d_ws, size_t ws_size,
                              hipStream_t stream) {
    const int*   inputs = (const int*)d_in[0];
    const float* w      = (const float*)d_in[1];
    const float* v      = (const float*)d_in[2];
    const float* bsc    = (const float*)d_in[3];
    const float* W1     = (const float*)d_in[4];
    const float* b1     = (const float*)d_in[5];
    const float* W2     = (const float*)d_in[6];
    const float* b2     = (const float*)d_in[7];
    float* out = (float*)d_out;

    char* ws = (char*)d_ws;
    __hip_bfloat16* xvT = (__hip_bfloat16*)(ws + XVT_OFF);
    char*  combo   = ws + COMBO_OFF;
    float* partial = (float*)(ws + PART_OFF);
    float* wval    = (float*)(ws + WVAL_OFF);
    float* consts  = (float*)(ws + CONST_OFF);

    prep_all<<<768 + 69, 256, 0, stream>>>(inputs, v, w, W1, W2, b1, b2, bsc,
                                           xvT, combo, wval, consts);
    ffm_main<<<NBB * 6, 256, 0, stream>>>(xvT, combo, partial);
    finalize<<<BATCH / 256, 256, 0, stream>>>(wval, consts, partial, out);
}